// Round 2
// baseline (4246.539 us; speedup 1.0000x reference)
//
#include <hip/hip_runtime.h>
#include <hip/hip_bf16.h>
#include <math.h>

using bf16 = __hip_bfloat16;
using short8 = __attribute__((ext_vector_type(8))) short;
using f32x4  = __attribute__((ext_vector_type(4))) float;

#define B_     128
#define T_     64
#define EMB_   1536
#define ACT_   12
#define STOCH_ 32
#define DETER_ 1024
#define HID_   1024
#define GRUN_  3072
#define GRUK_  2048
#define OBSK_  2560
#define OUTW_  1216   // 6*STOCH + DETER

// canonical f32 param block offsets (floats)
#define PW1   0
#define Pb1   45056
#define Pg1   46080
#define Pbn1  47104
#define Pbg   48128
#define Pgg   51200
#define Pbng  54272
#define Pb3   57344
#define Pg3   62464
#define Pbn3  67584
#define Pb4   72704
#define Pb5   73024
#define Pg5   74048
#define Pbn5  75072
#define Pb6   76096
#define PW4   76160
#define PW6   403840
#define PTOT  469376

__device__ inline float bf2f(bf16 v){ return __bfloat162float(v); }
__device__ inline bf16  f2bf(float v){ return __float2bfloat16(v); }
__device__ inline float elu_(float x){ return x > 0.f ? x : expm1f(x); }
__device__ inline float sigm_(float x){ return 1.f/(1.f+expf(-x)); }
__device__ inline float softplus_(float x){ return fmaxf(x,0.f) + log1pf(expf(-fabsf(x))); }
__device__ inline void stout(void* out, int dt, size_t i, float v){
  if(dt) ((bf16*)out)[i] = f2bf(v); else ((float*)out)[i] = v;
}

// 256-thread block reduction of two values (sum, sumsq)
__device__ inline void block_reduce2(float& a, float& b, float* sm){
  __syncthreads();
  for(int off=32; off>0; off>>=1){
    a += __shfl_down(a, off);
    b += __shfl_down(b, off);
  }
  int w = threadIdx.x >> 6;
  if((threadIdx.x & 63) == 0){ sm[2*w] = a; sm[2*w+1] = b; }
  __syncthreads();
  a = sm[0]+sm[2]+sm[4]+sm[6];
  b = sm[1]+sm[3]+sm[5]+sm[7];
}

// ---- detect float dtype from embed buffer: dflag[0] = 1 if bf16, 0 if f32 ----
// f32 data: u16 at even index = low mantissa bits (uniform random) -> ~45% have exp8>140
// bf16 data: u16 at even index = N(0,1) bf16 -> exp8 <= ~130, count ~0
__global__ void k_detect_dtype(const unsigned short* emb, int* dflag){
  __shared__ int cnt;
  if(threadIdx.x==0) cnt = 0;
  __syncthreads();
  int c = 0;
  for(int i=threadIdx.x; i<2048; i+=256){
    unsigned short u = emb[2*i];
    int exp8 = (u >> 7) & 0xFF;
    if(exp8 > 140) c++;
  }
  atomicAdd(&cnt, c);
  __syncthreads();
  if(threadIdx.x==0) dflag[0] = (cnt < 100) ? 1 : 0;
}

// ---- detect is_first encoding: dflag[1] = 0 int32, 1 uint8, 2 bf16, 3 f32 ----
__global__ void k_detect_isf(const unsigned char* isf, int* dflag){
  __shared__ int f_bf, f_f32, f_u8;
  if(threadIdx.x==0){ f_bf=0; f_f32=0; f_u8=0; }
  __syncthreads();
  for(int i=threadIdx.x; i<B_*T_; i+=256){
    unsigned char c = isf[i];
    if(c == 0x3F){
      if((i & 3) == 1) atomicOr(&f_bf, 1);        // bf16 1.0 = [0x80, 0x3F] per element
      else if((i & 3) == 3) atomicOr(&f_f32, 1);  // f32 1.0 = [0,0,0x80,0x3F]
    }
    if(c == 1 && (i & 3) != 0) atomicOr(&f_u8, 1);
  }
  __syncthreads();
  if(threadIdx.x==0)
    dflag[1] = f_bf ? 2 : (f_f32 ? 3 : (f_u8 ? 1 : 0));
}

__global__ void k_zero(float* p, int n){
  int i = blockIdx.x*256 + threadIdx.x;
  if(i < n) p[i] = 0.f;
}

// ---- batched param conversion -> canonical f32 block ----
struct PDesc { const void* src[17]; int cum[18]; };
__global__ __launch_bounds__(256) void k_params(PDesc pd, float* dst, const int* dflag){
  int g = blockIdx.x*256 + threadIdx.x;
  if(g >= PTOT) return;
  int dt = dflag[0];
  int s = 0;
  while(g >= pd.cum[s+1]) s++;
  int off = g - pd.cum[s];
  dst[g] = dt ? bf2f(((const bf16*)pd.src[s])[off]) : ((const float*)pd.src[s])[off];
}

__global__ void k_cvt_bf(const void* src, bf16* dst, int n, const int* dflag){
  int dt = dflag[0];
  int i0 = (blockIdx.x*256 + threadIdx.x)*4;
  #pragma unroll
  for(int k=0;k<4;k++){
    int i = i0+k;
    if(i < n) dst[i] = dt ? ((const bf16*)src)[i] : f2bf(((const float*)src)[i]);
  }
}

__global__ void k_cvt_f(const void* src, float* dst, int n, const int* dflag){
  int dt = dflag[0];
  int i0 = (blockIdx.x*256 + threadIdx.x)*4;
  #pragma unroll
  for(int k=0;k<4;k++){
    int i = i0+k;
    if(i < n) dst[i] = dt ? bf2f(((const bf16*)src)[i]) : ((const float*)src)[i];
  }
}

// ---- tiled transpose: src[K][N] -> dst[N][K] (bf16 canonical), head = blockIdx.y ----
__global__ __launch_bounds__(256) void k_transpose(const void* src, bf16* dst, int K, int N, const int* dflag){
  __shared__ unsigned short t[64][72];
  int dt = dflag[0];
  int tilesN = N/64;
  int tk = blockIdx.x / tilesN, tn = blockIdx.x % tilesN;
  size_t hoff = (size_t)blockIdx.y * K * N;
  unsigned short* d = (unsigned short*)dst + hoff;
  int tx = threadIdx.x & 63, ty0 = threadIdx.x >> 6;
  int k0 = tk*64, n0 = tn*64;
  #pragma unroll
  for(int i=0;i<16;i++){
    int ty = ty0*16+i;
    size_t off = hoff + (size_t)(k0+ty)*N + n0+tx;
    unsigned short v;
    if(dt) v = ((const unsigned short*)src)[off];
    else { bf16 b = f2bf(((const float*)src)[off]); v = *(unsigned short*)&b; }
    t[ty][tx] = v;
  }
  __syncthreads();
  #pragma unroll
  for(int i=0;i<16;i++){ int ty = ty0*16+i; d[(size_t)(n0+ty)*K + k0+tx] = t[tx][ty]; }
}

// ---- phase A: mask, input MLP (K=44) + LN + elu -> x; build A2=[x, deter*m] ----
__global__ __launch_bounds__(256) void k_step_in(
    const float* actF, const void* isf, const int* dflag,
    const float* paramF,
    const float* stoch, const float* deter, float* determ, bf16* A2, int t)
{
  __shared__ float in44[48];
  __shared__ float sm[8];
  int b = blockIdx.x, tid = threadIdx.x;
  float m;
  {
    int enc = dflag[1];
    int idx = b*T_ + t;
    float fv;
    if(enc==0)      fv = (float)((const int*)isf)[idx];
    else if(enc==1) fv = (float)((const unsigned char*)isf)[idx];
    else if(enc==2) fv = bf2f(((const bf16*)isf)[idx]);
    else            fv = ((const float*)isf)[idx];
    m = (fv != 0.f) ? 0.f : 1.f;
  }
  if(tid < STOCH_)            in44[tid] = stoch[b*STOCH_+tid]*m;
  else if(tid < STOCH_+ACT_)  in44[tid] = actF[(size_t)(b*T_+t)*ACT_ + (tid-STOCH_)]*m;
  __syncthreads();
  const float* W1f = paramF + PW1;
  float z[4]; float s=0.f, s2=0.f;
  #pragma unroll
  for(int i=0;i<4;i++){
    int h = tid + 256*i;
    float acc = paramF[Pb1 + h];
    for(int k=0;k<STOCH_+ACT_;k++) acc += in44[k]*W1f[k*HID_ + h];
    z[i]=acc; s+=acc; s2+=acc*acc;
  }
  block_reduce2(s, s2, sm);
  float mean = s/HID_, var = s2/HID_ - mean*mean;
  float rstd = rsqrtf(fmaxf(var,0.f) + 1e-5f);
  #pragma unroll
  for(int i=0;i<4;i++){
    int h = tid + 256*i;
    float xv = (z[i]-mean)*rstd*paramF[Pg1+h] + paramF[Pbn1+h];
    A2[(size_t)b*GRUK_ + h] = f2bf(elu_(xv));
  }
  #pragma unroll
  for(int i=0;i<4;i++){
    int h = tid + 256*i;
    float dm = deter[b*DETER_+h]*m;
    determ[b*DETER_+h] = dm;
    A2[(size_t)b*GRUK_ + HID_ + h] = f2bf(dm);
  }
}

// ---- generic K-split MFMA GEMM ----
// mode 0: z2 = A2 @ WgT^T     (N=3072, K=2048, 8 parts x 24 col tiles -> 192 blocks)
// mode 1: bid<32:  z3 = deterB @ W3T[idx]^T  (N=1024, K=1024, 4 parts x 8)
//         bid>=32: z5 = [deterB|embB_t] @ W5T^T (N=1024, K=2560, 10 parts x 8)
__global__ __launch_bounds__(256) void k_gemm(
    int mode, int t,
    const bf16* A2, const bf16* deterB, const bf16* embB,
    const bf16* WgT, const bf16* W3T, const bf16* W5T,
    float* z2p, float* z3p, float* z5p, const int* ens_index)
{
  int bid = blockIdx.x;
  const bf16 *A0, *A1 = nullptr, *BT; float* Cp;
  int N, ldb, s0, s1 = 0, split, kbase, ct;
  if(mode == 0){
    ct = bid % 24; int kp = bid / 24;
    N = GRUN_; ldb = GRUK_; BT = WgT;
    Cp = z2p + (size_t)kp*B_*GRUN_;
    A0 = A2; s0 = GRUK_; split = GRUK_;
    kbase = kp*256;
  } else if(bid < 32){
    ct = bid & 7; int kp = bid >> 3;
    int idx = ens_index[t];
    N = HID_; ldb = DETER_; BT = W3T + (size_t)idx*DETER_*HID_;
    Cp = z3p + (size_t)kp*B_*HID_;
    A0 = deterB; s0 = DETER_; split = DETER_;
    kbase = kp*256;
  } else {
    int b2 = bid - 32;
    ct = b2 & 7; int kp = b2 >> 3;
    N = HID_; ldb = OBSK_; BT = W5T;
    Cp = z5p + (size_t)kp*B_*HID_;
    A0 = deterB; s0 = DETER_; split = DETER_;
    A1 = embB + (size_t)t*EMB_; s1 = T_*EMB_;
    kbase = kp*256;
  }
  int wave = threadIdx.x >> 6, lane = threadIdx.x & 63;
  int quad = lane >> 4, lo = lane & 15;
  f32x4 acc[2][8];
  #pragma unroll
  for(int r=0;r<2;r++)
    #pragma unroll
    for(int c=0;c<8;c++) acc[r][c] = (f32x4)0.f;
  int r0 = 32*wave + lo;
  for(int kk = kbase; kk < kbase+256; kk += 32){
    int kf = kk + quad*8;
    short8 af[2], bfg[8];
    if(kf < split){
      af[0] = *(const short8*)(const void*)(A0 + (size_t)r0*s0 + kf);
      af[1] = *(const short8*)(const void*)(A0 + (size_t)(r0+16)*s0 + kf);
    } else {
      af[0] = *(const short8*)(const void*)(A1 + (size_t)r0*s1 + (kf-split));
      af[1] = *(const short8*)(const void*)(A1 + (size_t)(r0+16)*s1 + (kf-split));
    }
    #pragma unroll
    for(int c=0;c<8;c++){
      int n = ct*128 + 16*c + lo;
      bfg[c] = *(const short8*)(const void*)(BT + (size_t)n*ldb + kf);
    }
    #pragma unroll
    for(int c=0;c<8;c++){
      acc[0][c] = __builtin_amdgcn_mfma_f32_16x16x32_bf16(af[0], bfg[c], acc[0][c], 0,0,0);
      acc[1][c] = __builtin_amdgcn_mfma_f32_16x16x32_bf16(af[1], bfg[c], acc[1][c], 0,0,0);
    }
  }
  #pragma unroll
  for(int r=0;r<2;r++)
    #pragma unroll
    for(int c=0;c<8;c++)
      #pragma unroll
      for(int g=0;g<4;g++){
        int row = 32*wave + 16*r + quad*4 + g;
        int col = ct*128 + 16*c + lo;
        Cp[(size_t)row*N + col] = acc[r][c][g];
      }
}

// ---- phase C: reduce z2 partials + bias, LN over 3072, GRU -> deter ----
__global__ __launch_bounds__(256) void k_gru(
    const float* z2p, const float* paramF, const int* dflag,
    const float* determ, float* deter, bf16* deterB, void* out, int t)
{
  __shared__ float sm[8];
  int b = blockIdx.x, tid = threadIdx.x;
  int dt = dflag[0];
  float zz[12]; float s=0.f, s2=0.f;
  #pragma unroll
  for(int i=0;i<12;i++){
    int h = tid + 256*i;
    float acc = paramF[Pbg + h];
    #pragma unroll
    for(int p=0;p<8;p++) acc += z2p[((size_t)p*B_ + b)*GRUN_ + h];
    zz[i]=acc; s+=acc; s2+=acc*acc;
  }
  block_reduce2(s, s2, sm);
  float mean = s/GRUN_, var = s2/GRUN_ - mean*mean;
  float rstd = rsqrtf(fmaxf(var,0.f) + 1e-5f);
  #pragma unroll
  for(int j=0;j<4;j++){
    int h0 = tid + 256*j;
    float lnr = (zz[j]   - mean)*rstd*paramF[Pgg+h0     ] + paramF[Pbng+h0     ];
    float lnc = (zz[j+4] - mean)*rstd*paramF[Pgg+h0+1024] + paramF[Pbng+h0+1024];
    float lnu = (zz[j+8] - mean)*rstd*paramF[Pgg+h0+2048] + paramF[Pbng+h0+2048];
    float reset = sigm_(lnr);
    float cand  = tanhf(reset*lnc);
    float upd   = sigm_(lnu - 1.f);          // UPDATE_BIAS
    float dn = upd*cand + (1.f-upd)*determ[b*DETER_+h0];
    deter[b*DETER_+h0]  = dn;
    deterB[b*DETER_+h0] = f2bf(dn);
    stout(out, dt, ((size_t)b*T_+t)*OUTW_ + 192 + h0, dn);
  }
}

// ---- phase E: reduce z3/z5, LN+elu -> hs/xo; dist matmuls (K=1024,N=64); outputs ----
__global__ __launch_bounds__(256) void k_heads(
    const float* z3p, const float* z5p, const float* paramF, const int* dflag,
    float* stoch, void* out, const int* ens_index, int t)
{
  __shared__ float hs[1024], xo[1024];
  __shared__ float sm[8];
  __shared__ float red[256];
  __shared__ float dsO[128];
  int b = blockIdx.x, tid = threadIdx.x;
  int dt = dflag[0];
  int idx = ens_index[t];
  float z3v[4], z5v[4]; float s3=0.f,q3=0.f,s5=0.f,q5=0.f;
  #pragma unroll
  for(int i=0;i<4;i++){
    int h = tid + 256*i;
    float a3 = paramF[Pb3 + idx*HID_ + h];
    #pragma unroll
    for(int p=0;p<4;p++)  a3 += z3p[((size_t)p*B_ + b)*HID_ + h];
    z3v[i]=a3; s3+=a3; q3+=a3*a3;
    float a5 = paramF[Pb5 + h];
    #pragma unroll
    for(int p=0;p<10;p++) a5 += z5p[((size_t)p*B_ + b)*HID_ + h];
    z5v[i]=a5; s5+=a5; q5+=a5*a5;
  }
  block_reduce2(s3, q3, sm);
  block_reduce2(s5, q5, sm);
  float m3=s3/HID_, v3=q3/HID_-m3*m3, r3=rsqrtf(fmaxf(v3,0.f)+1e-5f);
  float m5=s5/HID_, v5=q5/HID_-m5*m5, r5=rsqrtf(fmaxf(v5,0.f)+1e-5f);
  #pragma unroll
  for(int i=0;i<4;i++){
    int h = tid + 256*i;
    hs[h] = elu_((z3v[i]-m3)*r3*paramF[Pg3+idx*HID_+h] + paramF[Pbn3+idx*HID_+h]);
    xo[h] = elu_((z5v[i]-m5)*r5*paramF[Pg5+h] + paramF[Pbn5+h]);
  }
  __syncthreads();
  int j = tid & 63, cch = tid >> 6;
  {
    const float* W = paramF + PW4 + (size_t)idx*HID_*64;
    float a = 0.f;
    for(int k=cch*256; k<cch*256+256; k++) a += hs[k]*W[k*64 + j];
    red[tid] = a;
    __syncthreads();
    if(tid < 64) dsO[tid] = red[tid]+red[tid+64]+red[tid+128]+red[tid+192] + paramF[Pb4+idx*64+tid];
    __syncthreads();
    const float* W6f = paramF + PW6;
    a = 0.f;
    for(int k=cch*256; k<cch*256+256; k++) a += xo[k]*W6f[k*64 + j];
    red[tid] = a;
    __syncthreads();
    if(tid < 64) dsO[64+tid] = red[tid]+red[tid+64]+red[tid+128]+red[tid+192] + paramF[Pb6+tid];
    __syncthreads();
  }
  size_t ob = ((size_t)b*T_ + t)*OUTW_;
  if(tid < 32){
    float pm = dsO[tid];
    float ps = softplus_(dsO[32+tid]) + 0.1f;
    float om = dsO[64+tid];
    float os = softplus_(dsO[96+tid]) + 0.1f;
    stout(out, dt, ob+tid,      om);   // omean
    stout(out, dt, ob+32+tid,   os);   // ostd
    stout(out, dt, ob+64+tid,   om);   // post_stoch
    stout(out, dt, ob+96+tid,   pm);   // pmean
    stout(out, dt, ob+128+tid,  ps);   // pstd
    stout(out, dt, ob+160+tid,  pm);   // prior_stoch
    stoch[b*STOCH_+tid] = om;          // fp32 carry
  }
}

extern "C" void kernel_launch(void* const* d_in, const int* in_sizes, int n_in,
                              void* d_out, int out_size, void* d_ws, size_t ws_size,
                              hipStream_t stream)
{
  const void* embed  = d_in[0];
  const void* action = d_in[1];
  const void* isf    = d_in[2];
  const int*  ens_ix = (const int*)d_in[3];

  char* ws = (char*)d_ws;
  float* stoch  = (float*)(ws + 0);            // 16 KB
  float* deter  = (float*)(ws + 16384);        // 512 KB
  float* determ = (float*)(ws + 540672);       // 512 KB
  bf16*  A2     = (bf16*) (ws + 1064960);      // 512 KB
  bf16*  deterB = (bf16*) (ws + 1589248);      // 256 KB
  float* z2p    = (float*)(ws + 1851392);      // 12.6 MB (8 parts)
  float* z3p    = (float*)(ws + 14434304);     // 2 MB (4 parts)
  float* z5p    = (float*)(ws + 16531456);     // 5.2 MB (10 parts)
  bf16*  WgT    = (bf16*) (ws + 21774336);     // 12.6 MB
  bf16*  W3T    = (bf16*) (ws + 34357248);     // 10.5 MB
  bf16*  W5T    = (bf16*) (ws + 44843008);     // 5.2 MB
  float* paramF = (float*)(ws + 50085888);     // 1.88 MB
  bf16*  embB   = (bf16*) (ws + 51963392);     // 25.2 MB
  float* actF   = (float*)(ws + 77129216);     // 0.39 MB
  int*   dflag  = (int*)  (ws + 77522432);

  k_detect_dtype<<<1,256,0,stream>>>((const unsigned short*)embed, dflag);
  k_detect_isf<<<1,256,0,stream>>>((const unsigned char*)isf, dflag);
  k_zero<<<(B_*STOCH_ + B_*DETER_)/256, 256, 0, stream>>>(stoch, B_*STOCH_ + B_*DETER_);

  PDesc pd;
  const int srcidx[17] = {4,5,6,7, 9,10,11, 13,14,15, 17, 19,20,21, 23, 16, 22};
  const int sizes[17]  = {45056,1024,1024,1024, 3072,3072,3072, 5120,5120,5120,
                          320, 1024,1024,1024, 64, 327680, 65536};
  int cum = 0;
  for(int i=0;i<17;i++){ pd.src[i] = d_in[srcidx[i]]; pd.cum[i] = cum; cum += sizes[i]; }
  pd.cum[17] = cum;  // 469376
  k_params<<<(PTOT+255)/256, 256, 0, stream>>>(pd, paramF, dflag);

  k_cvt_bf<<<(B_*T_*EMB_)/1024, 256, 0, stream>>>(embed, embB, B_*T_*EMB_, dflag);
  k_cvt_f<<<(B_*T_*ACT_+1023)/1024, 256, 0, stream>>>(action, actF, B_*T_*ACT_, dflag);

  k_transpose<<<dim3((GRUK_/64)*(GRUN_/64),1), 256, 0, stream>>>(d_in[8],  WgT, GRUK_, GRUN_, dflag);
  k_transpose<<<dim3((DETER_/64)*(HID_/64),5), 256, 0, stream>>>(d_in[12], W3T, DETER_, HID_, dflag);
  k_transpose<<<dim3((OBSK_/64)*(HID_/64),1), 256, 0, stream>>>(d_in[18], W5T, OBSK_, HID_, dflag);

  for(int t=0; t<T_; t++){
    k_step_in<<<B_,256,0,stream>>>(actF, isf, dflag, paramF, stoch, deter, determ, A2, t);
    k_gemm<<<192,256,0,stream>>>(0, t, A2, deterB, embB, WgT, W3T, W5T, z2p, z3p, z5p, ens_ix);
    k_gru<<<B_,256,0,stream>>>(z2p, paramF, dflag, determ, deter, deterB, d_out, t);
    k_gemm<<<112,256,0,stream>>>(1, t, A2, deterB, embB, WgT, W3T, W5T, z2p, z3p, z5p, ens_ix);
    k_heads<<<B_,256,0,stream>>>(z3p, z5p, paramF, dflag, stoch, d_out, ens_ix, t);
  }
}

// Round 3
// 4041.910 us; speedup vs baseline: 1.0506x; 1.0506x over previous
//
#include <hip/hip_runtime.h>
#include <hip/hip_bf16.h>
#include <math.h>

using bf16 = __hip_bfloat16;
using short8 = __attribute__((ext_vector_type(8))) short;
using f32x4  = __attribute__((ext_vector_type(4))) float;

#define B_     128
#define T_     64
#define EMB_   1536
#define ACT_   12
#define STOCH_ 32
#define DETER_ 1024
#define HID_   1024
#define GRUN_  3072
#define GRUK_  2048
#define OBSK_  2560
#define OUTW_  1216   // 6*STOCH + DETER

// canonical f32 param block offsets (floats)
#define PW1   0
#define Pb1   45056
#define Pg1   46080
#define Pbn1  47104
#define Pbg   48128
#define Pgg   51200
#define Pbng  54272
#define Pb3   57344
#define Pg3   62464
#define Pbn3  67584
#define Pb4   72704
#define Pb5   73024
#define Pg5   74048
#define Pbn5  75072
#define Pb6   76096
#define PW4   76160
#define PW6   403840
#define PTOT  469376

__device__ inline float bf2f(bf16 v){ return __bfloat162float(v); }
__device__ inline bf16  f2bf(float v){ return __float2bfloat16(v); }
__device__ inline float elu_(float x){ return x > 0.f ? x : expm1f(x); }
__device__ inline float sigm_(float x){ return 1.f/(1.f+expf(-x)); }
__device__ inline float softplus_(float x){ return fmaxf(x,0.f) + log1pf(expf(-fabsf(x))); }
__device__ inline void stout(void* out, int dt, size_t i, float v){
  if(dt) ((bf16*)out)[i] = f2bf(v); else ((float*)out)[i] = v;
}
__device__ inline float maskv(const void* isf, int enc, int idx){
  float fv;
  if(enc==0)      fv = (float)((const int*)isf)[idx];
  else if(enc==1) fv = (float)((const unsigned char*)isf)[idx];
  else if(enc==2) fv = bf2f(((const bf16*)isf)[idx]);
  else            fv = ((const float*)isf)[idx];
  return (fv != 0.f) ? 0.f : 1.f;
}

// 256-thread block reduction of two values (sum, sumsq)
__device__ inline void block_reduce2(float& a, float& b, float* sm){
  __syncthreads();
  for(int off=32; off>0; off>>=1){
    a += __shfl_down(a, off);
    b += __shfl_down(b, off);
  }
  int w = threadIdx.x >> 6;
  if((threadIdx.x & 63) == 0){ sm[2*w] = a; sm[2*w+1] = b; }
  __syncthreads();
  a = sm[0]+sm[2]+sm[4]+sm[6];
  b = sm[1]+sm[3]+sm[5]+sm[7];
}

// ---- detect float dtype from embed buffer: dflag[0] = 1 if bf16, 0 if f32 ----
__global__ void k_detect_dtype(const unsigned short* emb, int* dflag){
  __shared__ int cnt;
  if(threadIdx.x==0) cnt = 0;
  __syncthreads();
  int c = 0;
  for(int i=threadIdx.x; i<2048; i+=256){
    unsigned short u = emb[2*i];
    int exp8 = (u >> 7) & 0xFF;
    if(exp8 > 140) c++;
  }
  atomicAdd(&cnt, c);
  __syncthreads();
  if(threadIdx.x==0) dflag[0] = (cnt < 100) ? 1 : 0;
}

// ---- detect is_first encoding: dflag[1] = 0 int32, 1 uint8, 2 bf16, 3 f32 ----
__global__ void k_detect_isf(const unsigned char* isf, int* dflag){
  __shared__ int f_bf, f_f32, f_u8;
  if(threadIdx.x==0){ f_bf=0; f_f32=0; f_u8=0; }
  __syncthreads();
  for(int i=threadIdx.x; i<B_*T_; i+=256){
    unsigned char c = isf[i];
    if(c == 0x3F){
      if((i & 3) == 1) atomicOr(&f_bf, 1);
      else if((i & 3) == 3) atomicOr(&f_f32, 1);
    }
    if(c == 1 && (i & 3) != 0) atomicOr(&f_u8, 1);
  }
  __syncthreads();
  if(threadIdx.x==0)
    dflag[1] = f_bf ? 2 : (f_f32 ? 3 : (f_u8 ? 1 : 0));
}

// ---- batched param conversion -> canonical f32 block ----
struct PDesc { const void* src[17]; int cum[18]; };
__global__ __launch_bounds__(256) void k_params(PDesc pd, float* dst, const int* dflag){
  int g = blockIdx.x*256 + threadIdx.x;
  if(g >= PTOT) return;
  int dt = dflag[0];
  int s = 0;
  while(g >= pd.cum[s+1]) s++;
  int off = g - pd.cum[s];
  dst[g] = dt ? bf2f(((const bf16*)pd.src[s])[off]) : ((const float*)pd.src[s])[off];
}

__global__ void k_cvt_bf(const void* src, bf16* dst, int n, const int* dflag){
  int dt = dflag[0];
  int i0 = (blockIdx.x*256 + threadIdx.x)*4;
  #pragma unroll
  for(int k=0;k<4;k++){
    int i = i0+k;
    if(i < n) dst[i] = dt ? ((const bf16*)src)[i] : f2bf(((const float*)src)[i]);
  }
}

__global__ void k_cvt_f(const void* src, float* dst, int n, const int* dflag){
  int dt = dflag[0];
  int i0 = (blockIdx.x*256 + threadIdx.x)*4;
  #pragma unroll
  for(int k=0;k<4;k++){
    int i = i0+k;
    if(i < n) dst[i] = dt ? bf2f(((const bf16*)src)[i]) : ((const float*)src)[i];
  }
}

// ---- tiled transpose: src[K][N] -> dst[N][K] (bf16 canonical), head = blockIdx.y ----
__global__ __launch_bounds__(256) void k_transpose(const void* src, bf16* dst, int K, int N, const int* dflag){
  __shared__ unsigned short t[64][72];
  int dt = dflag[0];
  int tilesN = N/64;
  int tk = blockIdx.x / tilesN, tn = blockIdx.x % tilesN;
  size_t hoff = (size_t)blockIdx.y * K * N;
  unsigned short* d = (unsigned short*)dst + hoff;
  int tx = threadIdx.x & 63, ty0 = threadIdx.x >> 6;
  int k0 = tk*64, n0 = tn*64;
  #pragma unroll
  for(int i=0;i<16;i++){
    int ty = ty0*16+i;
    size_t off = hoff + (size_t)(k0+ty)*N + n0+tx;
    unsigned short v;
    if(dt) v = ((const unsigned short*)src)[off];
    else { bf16 b = f2bf(((const float*)src)[off]); v = *(unsigned short*)&b; }
    t[ty][tx] = v;
  }
  __syncthreads();
  #pragma unroll
  for(int i=0;i<16;i++){ int ty = ty0*16+i; d[(size_t)(n0+ty)*K + k0+tx] = t[tx][ty]; }
}

// ---- MFMA GEMM: 128x32 output tile per block, K split over 4 waves, LDS reduce ----
// mode 0 (grid 192): z2p[part] = A2[128,2048] @ WgT tile (N=3072; ct=bid%96, part=bid/96, Kc=1024)
// mode 1 (grid 96):  bid<32:  z3 = deterB @ W3T[idx] tile (K=1024, 1 part)
//                    bid>=32: z5p[part] = [deterB|embB_t] @ W5T tile (Kc=1280, 2 parts)
__global__ __launch_bounds__(256) void k_gemm(
    int mode, int t,
    const bf16* A2, const bf16* deterB, const bf16* embB,
    const bf16* WgT, const bf16* W3T, const bf16* W5T,
    float* z2p, float* z3buf, float* z5p, const int* ens_index)
{
  __shared__ float red[8192];   // 32 KB: 2 slots x (16 frag-blocks x 256 floats)
  int bid = blockIdx.x;
  const bf16 *A0, *A1 = nullptr, *BT; float* Cdst;
  int N, ldb, s0, s1 = 0, split = 1<<30, k0, kc;
  if(mode == 0){
    int ct = bid % 96, part = bid / 96;
    N = GRUN_; ldb = GRUK_; BT = WgT + (size_t)ct*32*GRUK_;
    A0 = A2; s0 = GRUK_;
    k0 = part*1024; kc = 1024;
    Cdst = z2p + (size_t)part*B_*GRUN_ + ct*32;
  } else if(bid < 32){
    int ct = bid;
    int idx = ens_index[t];
    N = HID_; ldb = DETER_; BT = W3T + (size_t)idx*DETER_*HID_ + (size_t)ct*32*DETER_;
    A0 = deterB; s0 = DETER_;
    k0 = 0; kc = 1024;
    Cdst = z3buf + ct*32;
  } else {
    int b2 = bid - 32;
    int ct = b2 & 31, part = b2 >> 5;
    N = HID_; ldb = OBSK_; BT = W5T + (size_t)ct*32*OBSK_;
    A0 = deterB; s0 = DETER_; split = DETER_;
    A1 = embB + (size_t)t*EMB_; s1 = T_*EMB_;
    k0 = part*1280; kc = 1280;
    Cdst = z5p + (size_t)part*B_*HID_ + ct*32;
  }
  int tid = threadIdx.x;
  int wave = tid >> 6, lane = tid & 63;
  int quad = lane >> 4, lo = lane & 15;
  int kw0 = k0 + wave*(kc>>2), kw1 = kw0 + (kc>>2);
  f32x4 acc[8][2];
  #pragma unroll
  for(int rf=0;rf<8;rf++){ acc[rf][0]=(f32x4)0.f; acc[rf][1]=(f32x4)0.f; }
  for(int kk=kw0; kk<kw1; kk+=32){
    int kf = kk + quad*8;
    const bf16* Ab; int str, ko;
    if(kf < split){ Ab=A0; str=s0; ko=kf; } else { Ab=A1; str=s1; ko=kf-split; }
    short8 af[8], bfg[2];
    #pragma unroll
    for(int rf=0;rf<8;rf++)
      af[rf] = *(const short8*)(const void*)(Ab + (size_t)(16*rf+lo)*str + ko);
    #pragma unroll
    for(int c=0;c<2;c++)
      bfg[c] = *(const short8*)(const void*)(BT + (size_t)(16*c+lo)*ldb + kf);
    #pragma unroll
    for(int rf=0;rf<8;rf++){
      acc[rf][0] = __builtin_amdgcn_mfma_f32_16x16x32_bf16(af[rf], bfg[0], acc[rf][0], 0,0,0);
      acc[rf][1] = __builtin_amdgcn_mfma_f32_16x16x32_bf16(af[rf], bfg[1], acc[rf][1], 0,0,0);
    }
  }
  // cross-wave reduce: waves 2,3 dump -> waves 0,1 add -> waves 0,1 dump -> all sum pairs
  if(wave >= 2){
    #pragma unroll
    for(int rf=0;rf<8;rf++)
      #pragma unroll
      for(int c=0;c<2;c++)
        *(f32x4*)&red[(((wave-2)*16) + rf*2 + c)*256 + lane*4] = acc[rf][c];
  }
  __syncthreads();
  if(wave < 2){
    #pragma unroll
    for(int rf=0;rf<8;rf++)
      #pragma unroll
      for(int c=0;c<2;c++)
        acc[rf][c] += *(const f32x4*)&red[((wave*16) + rf*2 + c)*256 + lane*4];
  }
  __syncthreads();
  if(wave < 2){
    #pragma unroll
    for(int rf=0;rf<8;rf++)
      #pragma unroll
      for(int c=0;c<2;c++)
        *(f32x4*)&red[((wave*16) + rf*2 + c)*256 + lane*4] = acc[rf][c];
  }
  __syncthreads();
  #pragma unroll
  for(int i=0;i<4;i++){
    int r = (tid>>3) + 32*i;
    int col0 = (tid&7)*4;
    int rf = r>>4, rr = r&15, q = rr>>2, g = rr&3;
    f32x4 v;
    #pragma unroll
    for(int j=0;j<4;j++){
      int col = col0+j; int c = col>>4, lo2 = col&15;
      int lane2 = q*16+lo2;
      v[j] = red[(rf*2 + c)*256 + lane2*4 + g]
           + red[(16 + rf*2 + c)*256 + lane2*4 + g];
    }
    *(f32x4*)(Cdst + (size_t)r*N + col0) = v;
  }
}

// ---- reduce z2 parts + bias, LN over 3072, GRU -> deter ----
__global__ __launch_bounds__(256) void k_gru(
    const float* z2p, const float* paramF, const int* dflag,
    const float* determ, float* deter, bf16* deterB, void* out, int t)
{
  __shared__ float sm[8];
  int b = blockIdx.x, tid = threadIdx.x;
  int dt = dflag[0];
  float zz[12]; float s=0.f, s2=0.f;
  #pragma unroll
  for(int i=0;i<12;i++){
    int h = tid + 256*i;
    float acc = paramF[Pbg + h]
              + z2p[(size_t)b*GRUN_ + h]
              + z2p[(size_t)(B_ + b)*GRUN_ + h];
    zz[i]=acc; s+=acc; s2+=acc*acc;
  }
  block_reduce2(s, s2, sm);
  float mean = s/GRUN_, var = s2/GRUN_ - mean*mean;
  float rstd = rsqrtf(fmaxf(var,0.f) + 1e-5f);
  #pragma unroll
  for(int j=0;j<4;j++){
    int h0 = tid + 256*j;
    float lnr = (zz[j]   - mean)*rstd*paramF[Pgg+h0     ] + paramF[Pbng+h0     ];
    float lnc = (zz[j+4] - mean)*rstd*paramF[Pgg+h0+1024] + paramF[Pbng+h0+1024];
    float lnu = (zz[j+8] - mean)*rstd*paramF[Pgg+h0+2048] + paramF[Pbng+h0+2048];
    float reset = sigm_(lnr);
    float cand  = tanhf(reset*lnc);
    float upd   = sigm_(lnu - 1.f);          // UPDATE_BIAS
    float dn = upd*cand + (1.f-upd)*determ[b*DETER_+h0];
    deter[b*DETER_+h0]  = dn;
    deterB[b*DETER_+h0] = f2bf(dn);
    stout(out, dt, ((size_t)b*T_+t)*OUTW_ + 192 + h0, dn);
  }
}

// ---- tail: heads (LN+elu, dist matmuls, outputs) fused with step_in for t+1 ----
__global__ __launch_bounds__(256) void k_tail(
    const float* z3buf, const float* z5p, const float* paramF, const int* dflag,
    const float* actF, const void* isf,
    const float* deter, float* determ, bf16* A2,
    void* out, const int* ens_index, int t)
{
  __shared__ float hs[1024], xo[1024];
  __shared__ float sm[8];
  __shared__ float red[256];
  __shared__ float dsO[128];
  __shared__ float in44[48];
  int b = blockIdx.x, tid = threadIdx.x;
  int dt = dflag[0];
  int idx = ens_index[t];
  float z3v[4], z5v[4]; float s3=0.f,q3=0.f,s5=0.f,q5=0.f;
  #pragma unroll
  for(int i=0;i<4;i++){
    int h = tid + 256*i;
    float a3 = z3buf[(size_t)b*HID_ + h] + paramF[Pb3 + idx*HID_ + h];
    z3v[i]=a3; s3+=a3; q3+=a3*a3;
    float a5 = z5p[(size_t)b*HID_ + h] + z5p[(size_t)(B_ + b)*HID_ + h] + paramF[Pb5 + h];
    z5v[i]=a5; s5+=a5; q5+=a5*a5;
  }
  block_reduce2(s3, q3, sm);
  block_reduce2(s5, q5, sm);
  float m3=s3/HID_, v3=q3/HID_-m3*m3, r3=rsqrtf(fmaxf(v3,0.f)+1e-5f);
  float m5=s5/HID_, v5=q5/HID_-m5*m5, r5=rsqrtf(fmaxf(v5,0.f)+1e-5f);
  #pragma unroll
  for(int i=0;i<4;i++){
    int h = tid + 256*i;
    hs[h] = elu_((z3v[i]-m3)*r3*paramF[Pg3+idx*HID_+h] + paramF[Pbn3+idx*HID_+h]);
    xo[h] = elu_((z5v[i]-m5)*r5*paramF[Pg5+h] + paramF[Pbn5+h]);
  }
  __syncthreads();
  int j = tid & 63, cch = tid >> 6;
  {
    const float* W = paramF + PW4 + (size_t)idx*HID_*64;
    float a = 0.f;
    for(int k=cch*256; k<cch*256+256; k++) a += hs[k]*W[k*64 + j];
    red[tid] = a;
    __syncthreads();
    if(tid < 64) dsO[tid] = red[tid]+red[tid+64]+red[tid+128]+red[tid+192] + paramF[Pb4+idx*64+tid];
    __syncthreads();
    const float* W6f = paramF + PW6;
    a = 0.f;
    for(int k=cch*256; k<cch*256+256; k++) a += xo[k]*W6f[k*64 + j];
    red[tid] = a;
    __syncthreads();
    if(tid < 64) dsO[64+tid] = red[tid]+red[tid+64]+red[tid+128]+red[tid+192] + paramF[Pb6+tid];
    __syncthreads();
  }
  size_t ob = ((size_t)b*T_ + t)*OUTW_;
  if(tid < 32){
    float pm = dsO[tid];
    float ps = softplus_(dsO[32+tid]) + 0.1f;
    float om = dsO[64+tid];
    float os = softplus_(dsO[96+tid]) + 0.1f;
    stout(out, dt, ob+tid,      om);   // omean
    stout(out, dt, ob+32+tid,   os);   // ostd
    stout(out, dt, ob+64+tid,   om);   // post_stoch
    stout(out, dt, ob+96+tid,   pm);   // pmean
    stout(out, dt, ob+128+tid,  ps);   // pstd
    stout(out, dt, ob+160+tid,  pm);   // prior_stoch
  }
  // ---- step_in for t+1 (block-local stoch carry = dsO[64..95]) ----
  if(t+1 < T_){
    float m = maskv(isf, dflag[1], b*T_ + (t+1));
    if(tid < 32)       in44[tid] = dsO[64+tid]*m;
    else if(tid < 44)  in44[tid] = actF[(size_t)(b*T_+(t+1))*ACT_ + (tid-32)]*m;
    __syncthreads();
    const float* W1f = paramF + PW1;
    float z[4]; float s=0.f, s2=0.f;
    #pragma unroll
    for(int i=0;i<4;i++){
      int h = tid + 256*i;
      float acc = paramF[Pb1 + h];
      for(int k=0;k<STOCH_+ACT_;k++) acc += in44[k]*W1f[k*HID_ + h];
      z[i]=acc; s+=acc; s2+=acc*acc;
    }
    block_reduce2(s, s2, sm);
    float mean = s/HID_, var = s2/HID_ - mean*mean;
    float rstd = rsqrtf(fmaxf(var,0.f) + 1e-5f);
    #pragma unroll
    for(int i=0;i<4;i++){
      int h = tid + 256*i;
      float xv = (z[i]-mean)*rstd*paramF[Pg1+h] + paramF[Pbn1+h];
      A2[(size_t)b*GRUK_ + h] = f2bf(elu_(xv));
      float dm = deter[b*DETER_+h]*m;
      determ[b*DETER_+h] = dm;
      A2[(size_t)b*GRUK_ + HID_ + h] = f2bf(dm);
    }
  }
}

// ---- init: step_in for t=0 with zero carry state ----
__global__ __launch_bounds__(256) void k_init(
    const float* actF, const void* isf, const int* dflag,
    const float* paramF, float* determ, bf16* A2)
{
  __shared__ float in44[48];
  __shared__ float sm[8];
  int b = blockIdx.x, tid = threadIdx.x;
  float m = maskv(isf, dflag[1], b*T_);
  if(tid < 32)       in44[tid] = 0.f;
  else if(tid < 44)  in44[tid] = actF[(size_t)(b*T_)*ACT_ + (tid-32)]*m;
  __syncthreads();
  const float* W1f = paramF + PW1;
  float z[4]; float s=0.f, s2=0.f;
  #pragma unroll
  for(int i=0;i<4;i++){
    int h = tid + 256*i;
    float acc = paramF[Pb1 + h];
    for(int k=0;k<STOCH_+ACT_;k++) acc += in44[k]*W1f[k*HID_ + h];
    z[i]=acc; s+=acc; s2+=acc*acc;
  }
  block_reduce2(s, s2, sm);
  float mean = s/HID_, var = s2/HID_ - mean*mean;
  float rstd = rsqrtf(fmaxf(var,0.f) + 1e-5f);
  #pragma unroll
  for(int i=0;i<4;i++){
    int h = tid + 256*i;
    float xv = (z[i]-mean)*rstd*paramF[Pg1+h] + paramF[Pbn1+h];
    A2[(size_t)b*GRUK_ + h] = f2bf(elu_(xv));
    determ[b*DETER_+h] = 0.f;
    A2[(size_t)b*GRUK_ + HID_ + h] = f2bf(0.f);
  }
}

extern "C" void kernel_launch(void* const* d_in, const int* in_sizes, int n_in,
                              void* d_out, int out_size, void* d_ws, size_t ws_size,
                              hipStream_t stream)
{
  const void* embed  = d_in[0];
  const void* action = d_in[1];
  const void* isf    = d_in[2];
  const int*  ens_ix = (const int*)d_in[3];

  char* ws = (char*)d_ws;
  float* deter  = (float*)(ws + 0);            // 512 KB
  float* determ = (float*)(ws + 524288);       // 512 KB
  bf16*  A2     = (bf16*) (ws + 1048576);      // 512 KB
  bf16*  deterB = (bf16*) (ws + 1572864);      // 256 KB
  float* z2p    = (float*)(ws + 1835008);      // 3 MB  (2 parts x 128x3072 f32)
  float* z3buf  = (float*)(ws + 4980736);      // 512 KB
  float* z5p    = (float*)(ws + 5505024);      // 1 MB  (2 parts)
  bf16*  WgT    = (bf16*) (ws + 6553600);      // 12.6 MB
  bf16*  W3T    = (bf16*) (ws + 19136512);     // 10.5 MB
  bf16*  W5T    = (bf16*) (ws + 29622272);     // 5.2 MB
  float* paramF = (float*)(ws + 34865152);     // 1.88 MB
  bf16*  embB   = (bf16*) (ws + 36742656);     // 25.2 MB
  float* actF   = (float*)(ws + 61908480);     // 0.39 MB
  int*   dflag  = (int*)  (ws + 62306304);

  k_detect_dtype<<<1,256,0,stream>>>((const unsigned short*)embed, dflag);
  k_detect_isf<<<1,256,0,stream>>>((const unsigned char*)isf, dflag);

  PDesc pd;
  const int srcidx[17] = {4,5,6,7, 9,10,11, 13,14,15, 17, 19,20,21, 23, 16, 22};
  const int sizes[17]  = {45056,1024,1024,1024, 3072,3072,3072, 5120,5120,5120,
                          320, 1024,1024,1024, 64, 327680, 65536};
  int cum = 0;
  for(int i=0;i<17;i++){ pd.src[i] = d_in[srcidx[i]]; pd.cum[i] = cum; cum += sizes[i]; }
  pd.cum[17] = cum;  // 469376
  k_params<<<(PTOT+255)/256, 256, 0, stream>>>(pd, paramF, dflag);

  k_cvt_bf<<<(B_*T_*EMB_)/1024, 256, 0, stream>>>(embed, embB, B_*T_*EMB_, dflag);
  k_cvt_f<<<(B_*T_*ACT_+1023)/1024, 256, 0, stream>>>(action, actF, B_*T_*ACT_, dflag);

  k_transpose<<<dim3((GRUK_/64)*(GRUN_/64),1), 256, 0, stream>>>(d_in[8],  WgT, GRUK_, GRUN_, dflag);
  k_transpose<<<dim3((DETER_/64)*(HID_/64),5), 256, 0, stream>>>(d_in[12], W3T, DETER_, HID_, dflag);
  k_transpose<<<dim3((OBSK_/64)*(HID_/64),1), 256, 0, stream>>>(d_in[18], W5T, OBSK_, HID_, dflag);

  k_init<<<B_,256,0,stream>>>(actF, isf, dflag, paramF, determ, A2);

  for(int t=0; t<T_; t++){
    k_gemm<<<192,256,0,stream>>>(0, t, A2, deterB, embB, WgT, W3T, W5T, z2p, z3buf, z5p, ens_ix);
    k_gru<<<B_,256,0,stream>>>(z2p, paramF, dflag, determ, deter, deterB, d_out, t);
    k_gemm<<<96,256,0,stream>>>(1, t, A2, deterB, embB, WgT, W3T, W5T, z2p, z3buf, z5p, ens_ix);
    k_tail<<<B_,256,0,stream>>>(z3buf, z5p, paramF, dflag, actF, isf, deter, determ, A2, d_out, ens_ix, t);
  }
}